// Round 8
// baseline (26.562 us; speedup 1.0000x reference)
//
#include <hip/hip_runtime.h>
#include <math.h>

#define PN 256
#define BN 1024
#define AN 15
#define NBIN 36
#define NBT 64
#define NRAMA 40
#define HR 512       // residues per block (half pose)
#define CSTRIDE 13   // 12 dwords (atoms 0..3 xyz) + 1 pad
#define PADT 40      // padded omega row length

// 16/8-byte loads with only 4-B alignment guaranteed (legal on gfx950).
struct __attribute__((packed, aligned(4))) uf4 { float x, y, z, w; };
struct __attribute__((packed, aligned(4))) uf2 { float x, y; };

__device__ __forceinline__ int wrap36(int v) {
    v %= NBIN;
    if (v < 0) v += NBIN;
    return v;
}

__device__ __forceinline__ void crw(float t, float w[4]) {
    float t2 = t * t;
    float t3 = t2 * t;
    w[0] = -0.5f * t3 + t2 - 0.5f * t;
    w[1] =  1.5f * t3 - 2.5f * t2 + 1.0f;
    w[2] = -1.5f * t3 + 2.0f * t2 + 0.5f * t;
    w[3] =  0.5f * t3 - 0.5f * t2;
}

__device__ __forceinline__ void cross3(const float a[3], const float b[3], float o[3]) {
    o[0] = a[1] * b[2] - a[2] * b[1];
    o[1] = a[2] * b[0] - a[0] * b[2];
    o[2] = a[0] * b[1] - a[1] * b[0];
}

__device__ __forceinline__ float dot3(const float a[3], const float b[3]) {
    return a[0] * b[0] + a[1] * b[1] + a[2] * b[2];
}

// minimax atan poly; absmax 0.25 on summed output vs threshold 1.33 (R6/R7).
__device__ __forceinline__ float fast_atan2f(float y, float x) {
    float ax = fabsf(x), ay = fabsf(y);
    float mx = fmaxf(fmaxf(ax, ay), 1e-30f);
    float mn = fminf(ax, ay);
    float a  = mn * __builtin_amdgcn_rcpf(mx);
    float s  = a * a;
    float r  = fmaf(fmaf(fmaf(0.0208351f, s, -0.0851330f), s, 0.180141f), s, -0.3302995f);
    r = fmaf(r, s, 0.9998660f) * a;
    if (ay > ax)  r = 1.5707964f - r;
    if (x < 0.0f) r = 3.1415927f - r;
    return copysignf(r, y);
}

__device__ __forceinline__ float one_dihedral(
    int t, int btc, int off_r, int4 cn, bool real,
    const int* __restrict__ s_ta, const int* __restrict__ s_dsc,
    const int* __restrict__ s_bt, const int* __restrict__ s_off,
    const int* __restrict__ btype_g, const int* __restrict__ off_g,
    const float* __restrict__ cslab, const float* __restrict__ cp,
    int wbase, bool& tv)
{
    float pts[4][3];
    bool valid = true;
    #pragma unroll
    for (int at = 0; at < 4; ++at) {
        const int tabase  = ((btc * 3 + t) * 4 + at) * 3;
        const int a_ind   = s_ta[tabase + 0];
        const int c_ind   = s_ta[tabase + 1];
        const int n_bonds = s_ta[tabase + 2];
        int  g;
        bool va;
        if (a_ind >= 0) {
            g  = off_r + a_ind;
            va = true;
        } else {
            const int cc        = min(c_ind > 0 ? c_ind : 0, 1);
            const int nbr_block = cc ? cn.z : cn.x;
            const int nbr_conn  = cc ? cn.w : cn.y;
            const int nb        = nbr_block > 0 ? nbr_block : 0;
            const int lnb       = nb - wbase;
            int nbt  = ((unsigned)lnb < HR) ? s_bt[lnb]  : btype_g[nb];
            int noff = ((unsigned)lnb < HR) ? s_off[lnb] : off_g[nb];
            if (nbt < 0) nbt = 0;
            const int ncc = min(nbr_conn > 0 ? nbr_conn : 0, 1);
            const int nbb = min(n_bonds > 0 ? n_bonds : 0, 3);
            const int ds  = s_dsc[(nbt * 2 + ncc) * 4 + nbb];
            g  = noff + ds;
            va = (c_ind >= 0) && (nbr_block >= 0) && (ds >= 0);
        }
        valid = valid && va;
        bool hit = false;
        if ((unsigned)g < (unsigned)(BN * AN)) {
            const int gres = g / 15;
            const int gat  = g - gres * 15;
            const int lres = gres - wbase;
            if ((unsigned)lres < HR && gat < 4) {
                const float* s = cslab + lres * CSTRIDE + gat * 3;
                pts[at][0] = s[0];
                pts[at][1] = s[1];
                pts[at][2] = s[2];
                hit = true;
            }
        }
        if (!hit) {
            int gc = g > 0 ? g : 0;
            if (gc > BN * AN - 1) gc = BN * AN - 1;
            const float* c3 = cp + (size_t)gc * 3;
            pts[at][0] = c3[0];
            pts[at][1] = c3[1];
            pts[at][2] = c3[2];
        }
    }
    tv = valid && real;

    float b1[3], b2[3], b3[3];
    #pragma unroll
    for (int k = 0; k < 3; ++k) {
        b1[k] = pts[1][k] - pts[0][k];
        b2[k] = pts[2][k] - pts[1][k];
        b3[k] = pts[3][k] - pts[2][k];
    }
    float n1[3], n2[3], b2n[3], m1[3];
    cross3(b1, b2, n1);
    cross3(b2, b3, n2);
    const float inv = __builtin_amdgcn_rsqf(dot3(b2, b2));
    #pragma unroll
    for (int k = 0; k < 3; ++k) b2n[k] = b2[k] * inv;
    cross3(n1, b2n, m1);
    return fast_atan2f(dot3(m1, n2), dot3(n1, n2));
}

// 2 threads per residue, role split by wave (wave-uniform, no divergence):
//   role A (tid < HR):  phi dihedral + full rama path
//   role B (tid >= HR): psi + omega dihedrals + omega eval
// Grid 512 blocks -> 2 blocks/CU resident -> 32 waves/CU (VGPR<=64 forced).
// Each block writes one partial pair to ws; a tiny combine kernel sums.
__global__ __launch_bounds__(1024, 8) void bb_torsion_kernel(
    const float* __restrict__ coords,
    const int*   __restrict__ off,
    const int*   __restrict__ btype,
    const int*   __restrict__ conn,
    const int*   __restrict__ dsc,
    const int*   __restrict__ rama_tbl_ind,
    const int*   __restrict__ upper_conn,
    const int*   __restrict__ is_pro,
    const int*   __restrict__ tor_atoms,
    const float* __restrict__ rama_tables,
    const float* __restrict__ omega_tables,
    const float* __restrict__ rama_params,
    const float* __restrict__ omega_params,
    float*       __restrict__ part)          // (PN, 2 halves, 2 scores)
{
    const int tid   = threadIdx.x;
    const int p     = blockIdx.x >> 1;
    const int half  = blockIdx.x & 1;
    const int wbase = half * HR;
    const bool roleA = tid < HR;
    const int lr = tid & (HR - 1);
    const int gr = wbase + lr;
    const int pb = p * BN + gr;

    const float* cp      = coords + (size_t)p * (BN * AN) * 3;
    const int*   btype_g = btype + p * BN;
    const int*   off_g   = off   + p * BN;

    __shared__ float cslab[HR * CSTRIDE];
    __shared__ int   s_bt[HR];
    __shared__ int   s_off[HR];
    __shared__ float s_psi[HR];
    __shared__ float s_tv1[HR];
    __shared__ int   s_ta[NBT * 36];
    __shared__ int   s_dsc[NBT * 8];
    __shared__ int   s_rti[NBT * 2];
    __shared__ int   s_uc[NBT];
    __shared__ int   s_ip[NBT];
    __shared__ float s_rp[NRAMA * 4];
    __shared__ float s_ot2[2 * PADT];
    __shared__ float s_op[4];
    __shared__ float swr[16], swo[16];

    const int off_r  = off_g[gr];
    const int bt_raw = btype_g[gr];
    if (roleA) { s_bt[lr] = bt_raw; s_off[lr] = off_r; }
    {
        const float* src = cp + (size_t)off_r * 3;
        float* d = cslab + lr * CSTRIDE;
        if (roleA) {
            const uf4 v0 = *(const uf4*)(src);
            const uf2 v1 = *(const uf2*)(src + 4);
            d[0] = v0.x; d[1] = v0.y; d[2] = v0.z; d[3] = v0.w;
            d[4] = v1.x; d[5] = v1.y;
        } else {
            const uf4 v0 = *(const uf4*)(src + 6);
            const uf2 v1 = *(const uf2*)(src + 10);
            d[6] = v0.x; d[7] = v0.y; d[8] = v0.z; d[9] = v0.w;
            d[10] = v1.x; d[11] = v1.y;
        }
    }
    const int4 cn = *(const int4*)(conn + pb * 4);
    if (tid < NBT * 36)        s_ta[tid]        = tor_atoms[tid];
    if (tid + 1024 < NBT * 36) s_ta[tid + 1024] = tor_atoms[tid + 1024];
    if (tid + 2048 < NBT * 36) s_ta[tid + 2048] = tor_atoms[tid + 2048];
    if (tid < NBT * 8)   s_dsc[tid] = dsc[tid];
    if (tid < NBT * 2)   s_rti[tid] = rama_tbl_ind[tid];
    if (tid < NBT)       { s_uc[tid] = upper_conn[tid]; s_ip[tid] = is_pro[tid]; }
    if (tid < NRAMA * 4) s_rp[tid] = rama_params[tid];
    if (tid < 2 * PADT)  {
        const int t = tid / PADT, k = tid - t * PADT;
        s_ot2[tid] = omega_tables[t * NBIN + (k + 35) % 36];
    }
    if (tid < 4)         s_op[tid] = omega_params[tid];
    __syncthreads();

    const bool real = bt_raw >= 0;
    const int  btc  = real ? bt_raw : 0;

    float dih0 = 0.0f, dih2 = 0.0f;
    bool  tv0 = false, tv2 = false;
    int   ri = 0;
    float xA = 0.0f;

    if (roleA) {
        dih0 = one_dihedral(0, btc, off_r, cn, real, s_ta, s_dsc, s_bt, s_off,
                            btype_g, off_g, cslab, cp, wbase, tv0);
        int uc = s_uc[btc];
        uc = min(uc < 0 ? 0 : uc, 1);
        const int nxt = uc ? cn.z : cn.x;
        const int nb2 = nxt > 0 ? nxt : 0;
        const int lnb2 = nb2 - wbase;
        int nbt2 = ((unsigned)lnb2 < HR) ? s_bt[lnb2] : btype_g[nb2];
        if (nbt2 < 0) nbt2 = 0;
        const int ipn = (nxt >= 0) ? s_ip[nbt2] : 0;
        ri = s_rti[btc * 2 + ipn];
        xA = (dih0 - s_rp[ri * 4 + 0]) * __builtin_amdgcn_rcpf(s_rp[ri * 4 + 2]);
    } else {
        bool tv1;
        const float dih1 = one_dihedral(1, btc, off_r, cn, real, s_ta, s_dsc,
                                        s_bt, s_off, btype_g, off_g, cslab, cp,
                                        wbase, tv1);
        dih2 = one_dihedral(2, btc, off_r, cn, real, s_ta, s_dsc, s_bt, s_off,
                            btype_g, off_g, cslab, cp, wbase, tv2);
        s_psi[lr] = dih1;
        s_tv1[lr] = tv1 ? 1.0f : 0.0f;
    }
    __syncthreads();

    float r_contrib = 0.0f, o_contrib = 0.0f;
    if (roleA) {
        const float psi  = s_psi[lr];
        const bool  tv1r = s_tv1[lr] != 0.0f;
        const float y = (psi - s_rp[ri * 4 + 1]) * __builtin_amdgcn_rcpf(s_rp[ri * 4 + 3]);
        const float ix0 = floorf(xA);
        const float iy0 = floorf(y);
        const float fx = xA - ix0;
        const float fy = y - iy0;
        const int xs0 = wrap36((int)ix0 - 1);
        const int ys0 = wrap36((int)iy0 - 1);

        float wx[4], wy[4];
        crw(fx, wx);
        crw(fy, wy);

        const float* rt = rama_tables + (size_t)ri * NBIN * NBIN;
        float er = 0.0f;
        #pragma unroll
        for (int i = 0; i < 4; ++i) {
            int xi = xs0 + i;
            if (xi >= NBIN) xi -= NBIN;
            const float* rrow = rt + xi * NBIN;
            float r0, r1, r2, r3;
            if (ys0 <= NBIN - 4) {
                const uf4 v = *(const uf4*)(rrow + ys0);
                r0 = v.x; r1 = v.y; r2 = v.z; r3 = v.w;
            } else {
                int y1 = ys0 + 1, y2 = ys0 + 2, y3 = ys0 + 3;
                if (y1 >= NBIN) y1 -= NBIN;
                if (y2 >= NBIN) y2 -= NBIN;
                if (y3 >= NBIN) y3 -= NBIN;
                r0 = rrow[ys0]; r1 = rrow[y1]; r2 = rrow[y2]; r3 = rrow[y3];
            }
            er = fmaf(wx[i],
                      fmaf(wy[0], r0, fmaf(wy[1], r1, fmaf(wy[2], r2, wy[3] * r3))),
                      er);
        }
        r_contrib = (tv0 && tv1r) ? er : 0.0f;
    } else {
        const int oi = s_ip[btc];
        const float z = (dih2 - s_op[oi * 2 + 0]) * __builtin_amdgcn_rcpf(s_op[oi * 2 + 1]);
        const float iz0 = floorf(z);
        const float fz = z - iz0;
        const int izw = wrap36((int)iz0);
        float wz[4];
        crw(fz, wz);
        const float* ot = s_ot2 + oi * PADT + izw;
        const float eo = wz[0] * ot[0] + wz[1] * ot[1] + wz[2] * ot[2] + wz[3] * ot[3];
        o_contrib = tv2 ? eo : 0.0f;
    }

    float r = r_contrib;
    float o = o_contrib;
    #pragma unroll
    for (int d = 32; d > 0; d >>= 1) {
        r += __shfl_down(r, d);
        o += __shfl_down(o, d);
    }
    const int wid = tid >> 6;
    if ((tid & 63) == 0) {
        swr[wid] = r;
        swo[wid] = o;
    }
    __syncthreads();
    if (tid < 64) {
        float R = (tid < 16) ? swr[tid] : 0.0f;
        float O = (tid < 16) ? swo[tid] : 0.0f;
        #pragma unroll
        for (int d = 8; d > 0; d >>= 1) {
            R += __shfl_down(R, d);
            O += __shfl_down(O, d);
        }
        if (tid == 0) {
            part[(p * 2 + half) * 2 + 0] = R;   // disjoint slots: deterministic
            part[(p * 2 + half) * 2 + 1] = O;
        }
    }
}

__global__ __launch_bounds__(256) void bb_combine(const float* __restrict__ part,
                                                  float* __restrict__ out)
{
    const int p = blockIdx.x * 256 + threadIdx.x;
    if (p < PN) {
        out[p]      = part[(p * 2 + 0) * 2 + 0] + part[(p * 2 + 1) * 2 + 0];
        out[PN + p] = part[(p * 2 + 0) * 2 + 1] + part[(p * 2 + 1) * 2 + 1];
    }
}

extern "C" void kernel_launch(void* const* d_in, const int* in_sizes, int n_in,
                              void* d_out, int out_size, void* d_ws, size_t ws_size,
                              hipStream_t stream) {
    const float* coords        = (const float*)d_in[0];
    const int*   off           = (const int*)d_in[1];
    const int*   btype         = (const int*)d_in[2];
    const int*   conn          = (const int*)d_in[3];
    const int*   dsc           = (const int*)d_in[4];
    const int*   rama_tbl_ind  = (const int*)d_in[5];
    const int*   upper_conn    = (const int*)d_in[6];
    const int*   is_pro        = (const int*)d_in[7];
    const int*   tor_atoms     = (const int*)d_in[8];
    const float* rama_tables   = (const float*)d_in[9];
    const float* omega_tables  = (const float*)d_in[10];
    const float* rama_params   = (const float*)d_in[11];
    const float* omega_params  = (const float*)d_in[12];
    float* out  = (float*)d_out;
    float* part = (float*)d_ws;   // 256 poses * 2 halves * 2 scores = 4 KB

    bb_torsion_kernel<<<PN * 2, 1024, 0, stream>>>(
        coords, off, btype, conn, dsc, rama_tbl_ind, upper_conn, is_pro,
        tor_atoms, rama_tables, omega_tables, rama_params, omega_params, part);
    bb_combine<<<1, 256, 0, stream>>>(part, out);
}

// Round 9
// 22.780 us; speedup vs baseline: 1.1660x; 1.1660x over previous
//
#include <hip/hip_runtime.h>
#include <math.h>

#define PN 256
#define BN 1024
#define AN 15
#define NBIN 36
#define NBT 64
#define NRAMA 40
#define CSTRIDE 13   // 12 dwords (atoms 0..3 xyz) + 1 pad
#define PADT 40      // padded omega row length

// 16/8-byte loads with only 4-B alignment guaranteed (legal on gfx950).
struct __attribute__((packed, aligned(4))) uf4 { float x, y, z, w; };

__device__ __forceinline__ int wrap36(int v) {
    v %= NBIN;
    if (v < 0) v += NBIN;
    return v;
}

__device__ __forceinline__ void crw(float t, float w[4]) {
    float t2 = t * t;
    float t3 = t2 * t;
    w[0] = -0.5f * t3 + t2 - 0.5f * t;
    w[1] =  1.5f * t3 - 2.5f * t2 + 1.0f;
    w[2] = -1.5f * t3 + 2.0f * t2 + 0.5f * t;
    w[3] =  0.5f * t3 - 0.5f * t2;
}

__device__ __forceinline__ void cross3(const float a[3], const float b[3], float o[3]) {
    o[0] = a[1] * b[2] - a[2] * b[1];
    o[1] = a[2] * b[0] - a[0] * b[2];
    o[2] = a[0] * b[1] - a[1] * b[0];
}

__device__ __forceinline__ float dot3(const float a[3], const float b[3]) {
    return a[0] * b[0] + a[1] * b[1] + a[2] * b[2];
}

// minimax atan poly; absmax 0.25 on summed output vs threshold 1.33 (R6-R8).
__device__ __forceinline__ float fast_atan2f(float y, float x) {
    float ax = fabsf(x), ay = fabsf(y);
    float mx = fmaxf(fmaxf(ax, ay), 1e-30f);
    float mn = fminf(ax, ay);
    float a  = mn * __builtin_amdgcn_rcpf(mx);
    float s  = a * a;
    float r  = fmaf(fmaf(fmaf(0.0208351f, s, -0.0851330f), s, 0.180141f), s, -0.3302995f);
    r = fmaf(r, s, 0.9998660f) * a;
    if (ay > ax)  r = 1.5707964f - r;
    if (x < 0.0f) r = 3.1415927f - r;
    return copysignf(r, y);
}

__device__ __forceinline__ float one_dihedral(
    int t, int btc, int off_r, int4 cn, bool real,
    const int* __restrict__ s_ta, const int* __restrict__ s_dsc,
    const int* __restrict__ s_bt, const int* __restrict__ s_off,
    const float* __restrict__ cslab, const float* __restrict__ cp,
    bool& tv)
{
    float pts[4][3];
    bool valid = true;
    #pragma unroll
    for (int at = 0; at < 4; ++at) {
        const int tabase  = ((btc * 3 + t) * 4 + at) * 3;
        const int a_ind   = s_ta[tabase + 0];
        const int c_ind   = s_ta[tabase + 1];
        const int n_bonds = s_ta[tabase + 2];
        int  g;
        bool va;
        if (a_ind >= 0) {
            g  = off_r + a_ind;
            va = true;
        } else {
            const int cc        = min(c_ind > 0 ? c_ind : 0, 1);
            const int nbr_block = cc ? cn.z : cn.x;
            const int nbr_conn  = cc ? cn.w : cn.y;
            const int nb        = nbr_block > 0 ? nbr_block : 0;
            int nbt  = s_bt[nb];
            int noff = s_off[nb];
            if (nbt < 0) nbt = 0;
            const int ncc = min(nbr_conn > 0 ? nbr_conn : 0, 1);
            const int nbb = min(n_bonds > 0 ? n_bonds : 0, 3);
            const int ds  = s_dsc[(nbt * 2 + ncc) * 4 + nbb];
            g  = noff + ds;
            va = (c_ind >= 0) && (nbr_block >= 0) && (ds >= 0);
        }
        valid = valid && va;
        bool hit = false;
        if ((unsigned)g < (unsigned)(BN * AN)) {
            const int gres = g / 15;
            const int gat  = g - gres * 15;
            if (gat < 4) {
                const float* s = cslab + gres * CSTRIDE + gat * 3;
                pts[at][0] = s[0];
                pts[at][1] = s[1];
                pts[at][2] = s[2];
                hit = true;
            }
        }
        if (!hit) {
            int gc = g > 0 ? g : 0;
            if (gc > BN * AN - 1) gc = BN * AN - 1;
            const float* c3 = cp + (size_t)gc * 3;
            pts[at][0] = c3[0];
            pts[at][1] = c3[1];
            pts[at][2] = c3[2];
        }
    }
    tv = valid && real;

    float b1[3], b2[3], b3[3];
    #pragma unroll
    for (int k = 0; k < 3; ++k) {
        b1[k] = pts[1][k] - pts[0][k];
        b2[k] = pts[2][k] - pts[1][k];
        b3[k] = pts[3][k] - pts[2][k];
    }
    float n1[3], n2[3], b2n[3], m1[3];
    cross3(b1, b2, n1);
    cross3(b2, b3, n2);
    const float inv = __builtin_amdgcn_rsqf(dot3(b2, b2));
    #pragma unroll
    for (int k = 0; k < 3; ++k) b2n[k] = b2[k] * inv;
    cross3(n1, b2n, m1);
    return fast_atan2f(dot3(m1, n2), dot3(n1, n2));
}

// One block per pose, 1024 threads, single dispatch.
// launch_bounds(1024,4): grid caps occupancy at 4 waves/SIMD anyway, so give
// the register allocator the full 128-VGPR budget to keep load chains in
// flight (R8 post-mortem: latency-bound, VGPR=68 was starving the scheduler).
__global__ __launch_bounds__(1024, 4) void bb_torsion_kernel(
    const float* __restrict__ coords,
    const int*   __restrict__ off,
    const int*   __restrict__ btype,
    const int*   __restrict__ conn,
    const int*   __restrict__ dsc,
    const int*   __restrict__ rama_tbl_ind,
    const int*   __restrict__ upper_conn,
    const int*   __restrict__ is_pro,
    const int*   __restrict__ tor_atoms,
    const float* __restrict__ rama_tables,
    const float* __restrict__ omega_tables,
    const float* __restrict__ rama_params,
    const float* __restrict__ omega_params,
    float*       __restrict__ out)
{
    const int tid = threadIdx.x;
    const int p   = blockIdx.x;
    const int pb  = p * BN + tid;

    const float* cp = coords + (size_t)p * (BN * AN) * 3;

    __shared__ float cslab[BN * CSTRIDE];
    __shared__ int   s_bt[BN];
    __shared__ int   s_off[BN];
    __shared__ int   s_ta[NBT * 36];
    __shared__ int   s_dsc[NBT * 8];
    __shared__ int   s_rti[NBT * 2];
    __shared__ int   s_uc[NBT];
    __shared__ int   s_ip[NBT];
    __shared__ float s_rp[NRAMA * 4];
    __shared__ float s_ot2[2 * PADT];
    __shared__ float s_op[4];
    __shared__ float swr[16], swo[16];

    // ---- staging ----
    const int off_r  = off[pb];
    const int bt_raw = btype[pb];
    s_off[tid] = off_r;
    s_bt[tid]  = bt_raw;
    {
        const float* src = cp + (size_t)off_r * 3;
        const uf4 v0 = *(const uf4*)(src);
        const uf4 v1 = *(const uf4*)(src + 4);
        const uf4 v2 = *(const uf4*)(src + 8);
        float* d = cslab + tid * CSTRIDE;
        d[0] = v0.x; d[1] = v0.y; d[2]  = v0.z; d[3]  = v0.w;
        d[4] = v1.x; d[5] = v1.y; d[6]  = v1.z; d[7]  = v1.w;
        d[8] = v2.x; d[9] = v2.y; d[10] = v2.z; d[11] = v2.w;
    }
    const int4 cn = *(const int4*)(conn + pb * 4);
    if (tid < NBT * 36)        s_ta[tid]        = tor_atoms[tid];
    if (tid + 1024 < NBT * 36) s_ta[tid + 1024] = tor_atoms[tid + 1024];
    if (tid + 2048 < NBT * 36) s_ta[tid + 2048] = tor_atoms[tid + 2048];
    if (tid < NBT * 8)   s_dsc[tid] = dsc[tid];
    if (tid < NBT * 2)   s_rti[tid] = rama_tbl_ind[tid];
    if (tid < NBT)       { s_uc[tid] = upper_conn[tid]; s_ip[tid] = is_pro[tid]; }
    if (tid < NRAMA * 4) s_rp[tid] = rama_params[tid];
    if (tid < 2 * PADT)  {
        const int t = tid / PADT, k = tid - t * PADT;
        s_ot2[tid] = omega_tables[t * NBIN + (k + 35) % 36];
    }
    if (tid < 4)         s_op[tid] = omega_params[tid];
    __syncthreads();

    const bool real = bt_raw >= 0;
    const int  btc  = real ? bt_raw : 0;

    // ---- phase 1: phi & psi dihedrals ----
    bool tv0, tv1;
    const float phi = one_dihedral(0, btc, off_r, cn, real, s_ta, s_dsc,
                                   s_bt, s_off, cslab, cp, tv0);
    const float psi = one_dihedral(1, btc, off_r, cn, real, s_ta, s_dsc,
                                   s_bt, s_off, cslab, cp, tv1);

    // ---- phase 2: rama indices + ISSUE all 16 table loads (branch-free) ----
    int uc = s_uc[btc];
    uc = min(uc < 0 ? 0 : uc, 1);
    const int nxt = uc ? cn.z : cn.x;
    const int nb2 = nxt > 0 ? nxt : 0;
    int nbt2 = s_bt[nb2];
    if (nbt2 < 0) nbt2 = 0;
    const int ipn = (nxt >= 0) ? s_ip[nbt2] : 0;
    const int ri  = s_rti[btc * 2 + ipn];

    const float x = (phi - s_rp[ri * 4 + 0]) * __builtin_amdgcn_rcpf(s_rp[ri * 4 + 2]);
    const float y = (psi - s_rp[ri * 4 + 1]) * __builtin_amdgcn_rcpf(s_rp[ri * 4 + 3]);
    const float ix0 = floorf(x);
    const float iy0 = floorf(y);
    const float fx = x - ix0;
    const float fy = y - iy0;

    int xi[4], yi[4];
    #pragma unroll
    for (int i = 0; i < 4; ++i) {
        xi[i] = wrap36((int)ix0 - 1 + i);
        yi[i] = wrap36((int)iy0 - 1 + i);
    }
    const float* rt = rama_tables + (size_t)ri * NBIN * NBIN;
    float rv[16];
    #pragma unroll
    for (int i = 0; i < 4; ++i) {
        const float* rrow = rt + xi[i] * NBIN;
        #pragma unroll
        for (int j = 0; j < 4; ++j) rv[i * 4 + j] = rrow[yi[j]];
    }

    // ---- phase 3: omega dihedral + eval (hides rama-load latency) ----
    bool tv2;
    const float omg = one_dihedral(2, btc, off_r, cn, real, s_ta, s_dsc,
                                   s_bt, s_off, cslab, cp, tv2);
    const int oi = s_ip[btc];
    const float z = (omg - s_op[oi * 2 + 0]) * __builtin_amdgcn_rcpf(s_op[oi * 2 + 1]);
    const float iz0 = floorf(z);
    const float fz = z - iz0;
    const int izw = wrap36((int)iz0);
    float wz[4];
    crw(fz, wz);
    const float* ot = s_ot2 + oi * PADT + izw;
    const float eo = wz[0] * ot[0] + wz[1] * ot[1] + wz[2] * ot[2] + wz[3] * ot[3];
    const float o_contrib = tv2 ? eo : 0.0f;

    // ---- phase 4: rama eval from prefetched registers ----
    float wx[4], wy[4];
    crw(fx, wx);
    crw(fy, wy);
    float er = 0.0f;
    #pragma unroll
    for (int i = 0; i < 4; ++i) {
        er = fmaf(wx[i],
                  fmaf(wy[0], rv[i * 4 + 0],
                  fmaf(wy[1], rv[i * 4 + 1],
                  fmaf(wy[2], rv[i * 4 + 2], wy[3] * rv[i * 4 + 3]))),
                  er);
    }
    const float r_contrib = (tv0 && tv1) ? er : 0.0f;

    // ---- reduce ----
    float r = r_contrib;
    float o = o_contrib;
    #pragma unroll
    for (int d = 32; d > 0; d >>= 1) {
        r += __shfl_down(r, d);
        o += __shfl_down(o, d);
    }
    const int wid = tid >> 6;
    if ((tid & 63) == 0) {
        swr[wid] = r;
        swo[wid] = o;
    }
    __syncthreads();
    if (tid < 64) {
        float R = (tid < 16) ? swr[tid] : 0.0f;
        float O = (tid < 16) ? swo[tid] : 0.0f;
        #pragma unroll
        for (int d = 8; d > 0; d >>= 1) {
            R += __shfl_down(R, d);
            O += __shfl_down(O, d);
        }
        if (tid == 0) {
            out[p]      = R;
            out[PN + p] = O;
        }
    }
}

extern "C" void kernel_launch(void* const* d_in, const int* in_sizes, int n_in,
                              void* d_out, int out_size, void* d_ws, size_t ws_size,
                              hipStream_t stream) {
    const float* coords        = (const float*)d_in[0];
    const int*   off           = (const int*)d_in[1];
    const int*   btype         = (const int*)d_in[2];
    const int*   conn          = (const int*)d_in[3];
    const int*   dsc           = (const int*)d_in[4];
    const int*   rama_tbl_ind  = (const int*)d_in[5];
    const int*   upper_conn    = (const int*)d_in[6];
    const int*   is_pro        = (const int*)d_in[7];
    const int*   tor_atoms     = (const int*)d_in[8];
    const float* rama_tables   = (const float*)d_in[9];
    const float* omega_tables  = (const float*)d_in[10];
    const float* rama_params   = (const float*)d_in[11];
    const float* omega_params  = (const float*)d_in[12];
    float* out = (float*)d_out;

    // Single dispatch (per-dispatch overhead measured ~3 us in R8).
    bb_torsion_kernel<<<PN, 1024, 0, stream>>>(
        coords, off, btype, conn, dsc, rama_tbl_ind, upper_conn, is_pro,
        tor_atoms, rama_tables, omega_tables, rama_params, omega_params, out);
}

// Round 10
// 22.712 us; speedup vs baseline: 1.1695x; 1.0030x over previous
//
#include <hip/hip_runtime.h>
#include <math.h>

#define PN 256
#define BN 1024
#define AN 15
#define NBIN 36
#define NBT 64
#define NRAMA 40
#define CSTRIDE 13   // 12 dwords (atoms 0..3 xyz) + 1 pad (coprime w/ 32 banks)
#define TASTRIDE 37  // padded tor_atoms row stride (36 -> 37, coprime w/ 32)
#define DSTRIDE 9    // padded dsc row stride (8 -> 9, coprime w/ 32)
#define PADT 40      // padded omega row length

// 16-byte load with only 4-B alignment guaranteed (legal on gfx950).
struct __attribute__((packed, aligned(4))) uf4 { float x, y, z, w; };

__device__ __forceinline__ int wrap36(int v) {
    v %= NBIN;
    if (v < 0) v += NBIN;
    return v;
}

__device__ __forceinline__ void crw(float t, float w[4]) {
    float t2 = t * t;
    float t3 = t2 * t;
    w[0] = -0.5f * t3 + t2 - 0.5f * t;
    w[1] =  1.5f * t3 - 2.5f * t2 + 1.0f;
    w[2] = -1.5f * t3 + 2.0f * t2 + 0.5f * t;
    w[3] =  0.5f * t3 - 0.5f * t2;
}

__device__ __forceinline__ void cross3(const float a[3], const float b[3], float o[3]) {
    o[0] = a[1] * b[2] - a[2] * b[1];
    o[1] = a[2] * b[0] - a[0] * b[2];
    o[2] = a[0] * b[1] - a[1] * b[0];
}

__device__ __forceinline__ float dot3(const float a[3], const float b[3]) {
    return a[0] * b[0] + a[1] * b[1] + a[2] * b[2];
}

// minimax atan poly; absmax 0.25 on summed output vs threshold 1.33 (R6-R9).
__device__ __forceinline__ float fast_atan2f(float y, float x) {
    float ax = fabsf(x), ay = fabsf(y);
    float mx = fmaxf(fmaxf(ax, ay), 1e-30f);
    float mn = fminf(ax, ay);
    float a  = mn * __builtin_amdgcn_rcpf(mx);
    float s  = a * a;
    float r  = fmaf(fmaf(fmaf(0.0208351f, s, -0.0851330f), s, 0.180141f), s, -0.3302995f);
    r = fmaf(r, s, 0.9998660f) * a;
    if (ay > ax)  r = 1.5707964f - r;
    if (x < 0.0f) r = 3.1415927f - r;
    return copysignf(r, y);
}

__device__ __forceinline__ float one_dihedral(
    int t, int btc, int off_r, int4 cn, bool real,
    const int* __restrict__ s_ta, const int* __restrict__ s_dsc,
    const int* __restrict__ s_bt, const int* __restrict__ s_off,
    const float* __restrict__ cslab, const float* __restrict__ cp,
    bool& tv)
{
    float pts[4][3];
    bool valid = true;
    #pragma unroll
    for (int at = 0; at < 4; ++at) {
        // padded stride: btc*37 spreads random btc across all 32 banks
        const int tabase  = btc * TASTRIDE + (t * 4 + at) * 3;
        const int a_ind   = s_ta[tabase + 0];
        const int c_ind   = s_ta[tabase + 1];
        const int n_bonds = s_ta[tabase + 2];
        int  g;
        bool va;
        if (a_ind >= 0) {
            g  = off_r + a_ind;
            va = true;
        } else {
            const int cc        = min(c_ind > 0 ? c_ind : 0, 1);
            const int nbr_block = cc ? cn.z : cn.x;
            const int nbr_conn  = cc ? cn.w : cn.y;
            const int nb        = nbr_block > 0 ? nbr_block : 0;
            int nbt  = s_bt[nb];
            int noff = s_off[nb];
            if (nbt < 0) nbt = 0;
            const int ncc = min(nbr_conn > 0 ? nbr_conn : 0, 1);
            const int nbb = min(n_bonds > 0 ? n_bonds : 0, 3);
            const int ds  = s_dsc[nbt * DSTRIDE + ncc * 4 + nbb];
            g  = noff + ds;
            va = (c_ind >= 0) && (nbr_block >= 0) && (ds >= 0);
        }
        valid = valid && va;
        bool hit = false;
        if ((unsigned)g < (unsigned)(BN * AN)) {
            const int gres = g / 15;
            const int gat  = g - gres * 15;
            if (gat < 4) {
                const float* s = cslab + gres * CSTRIDE + gat * 3;
                pts[at][0] = s[0];
                pts[at][1] = s[1];
                pts[at][2] = s[2];
                hit = true;
            }
        }
        if (!hit) {
            int gc = g > 0 ? g : 0;
            if (gc > BN * AN - 1) gc = BN * AN - 1;
            const float* c3 = cp + (size_t)gc * 3;
            pts[at][0] = c3[0];
            pts[at][1] = c3[1];
            pts[at][2] = c3[2];
        }
    }
    tv = valid && real;

    float b1[3], b2[3], b3[3];
    #pragma unroll
    for (int k = 0; k < 3; ++k) {
        b1[k] = pts[1][k] - pts[0][k];
        b2[k] = pts[2][k] - pts[1][k];
        b3[k] = pts[3][k] - pts[2][k];
    }
    float n1[3], n2[3], b2n[3], m1[3];
    cross3(b1, b2, n1);
    cross3(b2, b3, n2);
    const float inv = __builtin_amdgcn_rsqf(dot3(b2, b2));
    #pragma unroll
    for (int k = 0; k < 3; ++k) b2n[k] = b2[k] * inv;
    cross3(n1, b2n, m1);
    return fast_atan2f(dot3(m1, n2), dot3(n1, n2));
}

// One block per pose, 1024 threads, single dispatch.
__global__ __launch_bounds__(1024, 4) void bb_torsion_kernel(
    const float* __restrict__ coords,
    const int*   __restrict__ off,
    const int*   __restrict__ btype,
    const int*   __restrict__ conn,
    const int*   __restrict__ dsc,
    const int*   __restrict__ rama_tbl_ind,
    const int*   __restrict__ upper_conn,
    const int*   __restrict__ is_pro,
    const int*   __restrict__ tor_atoms,
    const float* __restrict__ rama_tables,
    const float* __restrict__ omega_tables,
    const float* __restrict__ rama_params,
    const float* __restrict__ omega_params,
    float*       __restrict__ out)
{
    const int tid = threadIdx.x;
    const int p   = blockIdx.x;
    const int pb  = p * BN + tid;

    const float* cp = coords + (size_t)p * (BN * AN) * 3;

    __shared__ float cslab[BN * CSTRIDE];        // 53248 B
    __shared__ int   s_bt[BN];
    __shared__ int   s_off[BN];
    __shared__ int   s_ta[NBT * TASTRIDE];       // 9472 B (padded)
    __shared__ int   s_dsc[NBT * DSTRIDE];       // 2304 B (padded)
    __shared__ int   s_rti[NBT * 2];
    __shared__ int   s_uc[NBT];
    __shared__ int   s_ip[NBT];
    __shared__ float s_rp[NRAMA * 4];
    __shared__ float s_ot2[2 * PADT];
    __shared__ float s_op[4];
    __shared__ float swr[16], swo[16];

    // ---- staging ----
    const int off_r  = off[pb];
    const int bt_raw = btype[pb];
    s_off[tid] = off_r;
    s_bt[tid]  = bt_raw;
    {
        const float* src = cp + (size_t)off_r * 3;
        const uf4 v0 = *(const uf4*)(src);
        const uf4 v1 = *(const uf4*)(src + 4);
        const uf4 v2 = *(const uf4*)(src + 8);
        float* d = cslab + tid * CSTRIDE;
        d[0] = v0.x; d[1] = v0.y; d[2]  = v0.z; d[3]  = v0.w;
        d[4] = v1.x; d[5] = v1.y; d[6]  = v1.z; d[7]  = v1.w;
        d[8] = v2.x; d[9] = v2.y; d[10] = v2.z; d[11] = v2.w;
    }
    const int4 cn = *(const int4*)(conn + pb * 4);
    // tor_atoms: 2304 entries, repack to padded stride 37
    #pragma unroll
    for (int k = 0; k < 3; ++k) {
        const int i = tid + k * 1024;
        if (i < NBT * 36) {
            const int row = i / 36;
            const int col = i - row * 36;
            s_ta[row * TASTRIDE + col] = tor_atoms[i];
        }
    }
    if (tid < NBT * 8) {
        const int row = tid >> 3;
        const int col = tid & 7;
        s_dsc[row * DSTRIDE + col] = dsc[tid];
    }
    if (tid < NBT * 2)   s_rti[tid] = rama_tbl_ind[tid];
    if (tid < NBT)       { s_uc[tid] = upper_conn[tid]; s_ip[tid] = is_pro[tid]; }
    if (tid < NRAMA * 4) s_rp[tid] = rama_params[tid];
    if (tid < 2 * PADT)  {
        const int t = tid / PADT, k = tid - t * PADT;
        s_ot2[tid] = omega_tables[t * NBIN + (k + 35) % 36];
    }
    if (tid < 4)         s_op[tid] = omega_params[tid];
    __syncthreads();

    const bool real = bt_raw >= 0;
    const int  btc  = real ? bt_raw : 0;

    // ---- phase 1: phi & psi ----
    bool tv0, tv1;
    const float phi = one_dihedral(0, btc, off_r, cn, real, s_ta, s_dsc,
                                   s_bt, s_off, cslab, cp, tv0);
    const float psi = one_dihedral(1, btc, off_r, cn, real, s_ta, s_dsc,
                                   s_bt, s_off, cslab, cp, tv1);

    // ---- phase 2: rama indices + issue all 16 table loads ----
    int uc = s_uc[btc];
    uc = min(uc < 0 ? 0 : uc, 1);
    const int nxt = uc ? cn.z : cn.x;
    const int nb2 = nxt > 0 ? nxt : 0;
    int nbt2 = s_bt[nb2];
    if (nbt2 < 0) nbt2 = 0;
    const int ipn = (nxt >= 0) ? s_ip[nbt2] : 0;
    const int ri  = s_rti[btc * 2 + ipn];

    const float x = (phi - s_rp[ri * 4 + 0]) * __builtin_amdgcn_rcpf(s_rp[ri * 4 + 2]);
    const float y = (psi - s_rp[ri * 4 + 1]) * __builtin_amdgcn_rcpf(s_rp[ri * 4 + 3]);
    const float ix0 = floorf(x);
    const float iy0 = floorf(y);
    const float fx = x - ix0;
    const float fy = y - iy0;

    int xi[4], yi[4];
    #pragma unroll
    for (int i = 0; i < 4; ++i) {
        xi[i] = wrap36((int)ix0 - 1 + i);
        yi[i] = wrap36((int)iy0 - 1 + i);
    }
    const float* rt = rama_tables + (size_t)ri * NBIN * NBIN;
    float rv[16];
    #pragma unroll
    for (int i = 0; i < 4; ++i) {
        const float* rrow = rt + xi[i] * NBIN;
        #pragma unroll
        for (int j = 0; j < 4; ++j) rv[i * 4 + j] = rrow[yi[j]];
    }

    // ---- phase 3: omega dihedral + eval (hides rama-load latency) ----
    bool tv2;
    const float omg = one_dihedral(2, btc, off_r, cn, real, s_ta, s_dsc,
                                   s_bt, s_off, cslab, cp, tv2);
    const int oi = s_ip[btc];
    const float z = (omg - s_op[oi * 2 + 0]) * __builtin_amdgcn_rcpf(s_op[oi * 2 + 1]);
    const float iz0 = floorf(z);
    const float fz = z - iz0;
    const int izw = wrap36((int)iz0);
    float wz[4];
    crw(fz, wz);
    const float* ot = s_ot2 + oi * PADT + izw;
    const float eo = wz[0] * ot[0] + wz[1] * ot[1] + wz[2] * ot[2] + wz[3] * ot[3];
    const float o_contrib = tv2 ? eo : 0.0f;

    // ---- phase 4: rama eval ----
    float wx[4], wy[4];
    crw(fx, wx);
    crw(fy, wy);
    float er = 0.0f;
    #pragma unroll
    for (int i = 0; i < 4; ++i) {
        er = fmaf(wx[i],
                  fmaf(wy[0], rv[i * 4 + 0],
                  fmaf(wy[1], rv[i * 4 + 1],
                  fmaf(wy[2], rv[i * 4 + 2], wy[3] * rv[i * 4 + 3]))),
                  er);
    }
    const float r_contrib = (tv0 && tv1) ? er : 0.0f;

    // ---- reduce ----
    float r = r_contrib;
    float o = o_contrib;
    #pragma unroll
    for (int d = 32; d > 0; d >>= 1) {
        r += __shfl_down(r, d);
        o += __shfl_down(o, d);
    }
    const int wid = tid >> 6;
    if ((tid & 63) == 0) {
        swr[wid] = r;
        swo[wid] = o;
    }
    __syncthreads();
    if (tid < 64) {
        float R = (tid < 16) ? swr[tid] : 0.0f;
        float O = (tid < 16) ? swo[tid] : 0.0f;
        #pragma unroll
        for (int d = 8; d > 0; d >>= 1) {
            R += __shfl_down(R, d);
            O += __shfl_down(O, d);
        }
        if (tid == 0) {
            out[p]      = R;
            out[PN + p] = O;
        }
    }
}

extern "C" void kernel_launch(void* const* d_in, const int* in_sizes, int n_in,
                              void* d_out, int out_size, void* d_ws, size_t ws_size,
                              hipStream_t stream) {
    const float* coords        = (const float*)d_in[0];
    const int*   off           = (const int*)d_in[1];
    const int*   btype         = (const int*)d_in[2];
    const int*   conn          = (const int*)d_in[3];
    const int*   dsc           = (const int*)d_in[4];
    const int*   rama_tbl_ind  = (const int*)d_in[5];
    const int*   upper_conn    = (const int*)d_in[6];
    const int*   is_pro        = (const int*)d_in[7];
    const int*   tor_atoms     = (const int*)d_in[8];
    const float* rama_tables   = (const float*)d_in[9];
    const float* omega_tables  = (const float*)d_in[10];
    const float* rama_params   = (const float*)d_in[11];
    const float* omega_params  = (const float*)d_in[12];
    float* out = (float*)d_out;

    bb_torsion_kernel<<<PN, 1024, 0, stream>>>(
        coords, off, btype, conn, dsc, rama_tbl_ind, upper_conn, is_pro,
        tor_atoms, rama_tables, omega_tables, rama_params, omega_params, out);
}